// Round 9
// baseline (301.975 us; speedup 1.0000x reference)
//
#include <hip/hip_runtime.h>
#include <math.h>

#define N1C 50176
#define N2C 12544
#define N3C 3136
#define NT_TILES (N2C * 8 / 64)   // 1568 conv tiles (64 cols each)

typedef __attribute__((ext_vector_type(8))) short bf16x8;
typedef __attribute__((ext_vector_type(4))) float f32x4;

__device__ __forceinline__ unsigned short f2bf(float f) {
    unsigned u = __builtin_bit_cast(unsigned, f);
    u += 0x7fffu + ((u >> 16) & 1u);
    return (unsigned short)(u >> 16);
}
// single-instruction RNE pack of 2 f32 -> 2 bf16
__device__ __forceinline__ unsigned cvtpk(float lo, float hi) {
    unsigned r;
    asm("v_cvt_pk_bf16_f32 %0, %1, %2" : "=v"(r) : "v"(lo), "v"(hi));
    return r;
}
__device__ __forceinline__ float bf2f(unsigned short u) {
    return __builtin_bit_cast(float, (unsigned)u << 16);
}
__device__ __forceinline__ float bflo(unsigned u) {
    return __builtin_bit_cast(float, u << 16);
}
__device__ __forceinline__ float bfhi(unsigned u) {
    return __builtin_bit_cast(float, u & 0xffff0000u);
}

// ---------------- fused prologue: transpose | mlp(off1+off2) | pad_w(W1,W2,W3) ----------------
#define TRB (N1C / 64)            // 784
#define MLB (2 * N2C * 9 / 256)   // 882  (first 441 -> A1, rest -> A2; boundary block-aligned)
#define PWB 112                   // (1024+9216+18432)/256

__device__ __forceinline__ void pad_one(int i, const float* __restrict__ W,
                                        unsigned short* __restrict__ Wp,
                                        int OC, int CIN, int KT) {
    int j = i & 7;
    int op = (i >> 3) & 31;
    int q = (i >> 8) & 3;
    int kt = (i >> 10) % KT;
    int g = i / (KT * 1024);
    int kp = kt * 32 + q * 8 + j;
    int t = kp / CIN, c = kp - t * CIN;
    int o = g * 32 + op;
    float v = (t < 9 && o < OC) ? W[(o * CIN + c) * 9 + t] : 0.f;
    Wp[i] = f2bf(v);
}

__global__ void prologue_kernel(const float* __restrict__ x, unsigned short* __restrict__ X0,
                                const float* __restrict__ off1, const float* __restrict__ off2,
                                const float* __restrict__ Wh, const float* __restrict__ bh,
                                const float* __restrict__ Wo, const float* __restrict__ bo,
                                float* __restrict__ A1, float* __restrict__ A2,
                                const float* __restrict__ W1, const float* __restrict__ W2,
                                const float* __restrict__ W3,
                                unsigned short* __restrict__ W1p, unsigned short* __restrict__ W2p,
                                unsigned short* __restrict__ W3p) {
    __shared__ float U[2304];     // transpose tile (1600 used) | A staging (2304)
    int blk = blockIdx.x;
    int tid = threadIdx.x;
    if (blk < TRB) {
        int n0 = blk * 64;
        for (int r = tid; r < 24 * 64; r += 256) {
            int cb = r >> 6;
            int nn = r & 63;
            U[nn * 25 + cb] = x[cb * N1C + n0 + nn];
        }
        __syncthreads();
        for (int w = tid; w < 64 * 24; w += 256) {
            int nn = w / 24;
            int u = w - nn * 24;
            X0[(n0 + nn) * 24 + u] = f2bf(U[nn * 25 + u]);
        }
    } else if (blk < TRB + MLB) {
        int bi = blk - TRB;
        int idx = bi * 256 + tid;
        const float* offp;
        if (idx < N2C * 9) offp = off1 + idx * 2;
        else offp = off2 + (idx - N2C * 9) * 2;
        float o0 = offp[0], o1 = offp[1];
        float out[9];
#pragma unroll
        for (int t = 0; t < 9; t++) out[t] = bo[t];
#pragma unroll
        for (int h = 0; h < 32; h++) {
            float hv = fmaxf(o0 * Wh[h] + o1 * Wh[32 + h] + bh[h], 0.f);
#pragma unroll
            for (int t = 0; t < 9; t++) out[t] += hv * Wo[h * 9 + t];
        }
#pragma unroll
        for (int t = 0; t < 9; t++) U[tid * 9 + t] = out[t];   // stride 9: conflict-free
        __syncthreads();
        float* dst = (bi < 441) ? (A1 + (size_t)bi * 2304)
                                : (A2 + (size_t)(bi - 441) * 2304);
        for (int i = tid; i < 2304; i += 256) dst[i] = U[i];   // coalesced
    } else {
        int i = (blk - TRB - MLB) * 256 + tid;
        if (i < 1024) pad_one(i, W1, W1p, 32, 3, 1);
        else if (i < 10240) pad_one(i - 1024, W2, W2p, 32, 32, 9);
        else pad_one(i - 10240, W3, W3p, 64, 32, 9);
    }
}

// ---------------- conv1: CIN=3 gather+weight -> LDS S -> MFMA (unchanged, verified) ----------------
template <int CIN, int MW, bool HAS_BN>   // instantiated with CIN=3 only
__global__ __launch_bounds__(256, 4)
void conv_kernel(const unsigned short* __restrict__ Xin,
                 const int* __restrict__ nbr,
                 const float* __restrict__ A,
                 const unsigned short* __restrict__ Wp,
                 const float* __restrict__ bias,
                 const float* __restrict__ bnsc,
                 const float* __restrict__ bnsh,
                 unsigned short* __restrict__ Yb,
                 double* __restrict__ Part) {
    constexpr int OC = MW * 16;
    constexpr int KREAL = 9 * CIN;
    constexpr int KROW = (KREAL + 31) & ~31;
    constexpr int KT = KROW / 32;
    constexpr int KSTR = KROW + 8;
    constexpr int PARTS = 256 / OC;
    constexpr int PCOLS = 64 / PARTS;
    constexpr int OSH = (OC == 32) ? 5 : 6;
    constexpr int YSTR = OC + 4;
    constexpr int SB1 = 64 * KSTR * 2;
    constexpr int SB2 = 64 * YSTR * 4 + PARTS * 2 * OC * 4;
    constexpr int SBYTES = SB1 > SB2 ? SB1 : SB2;
    __shared__ alignas(16) char Sraw[SBYTES];
    __shared__ float a_lds[8 * 81];
    short* S = (short*)Sraw;

    int tid = threadIdx.x;
    int tile = blockIdx.x;
    int n0 = tile * 8;

    for (int i = tid; i < 64 * KSTR; i += 256) S[i] = 0;   // zero pad slots
    for (int i = tid; i < 648; i += 256) a_lds[i] = A[(size_t)n0 * 81 + i];
    __syncthreads();
    if (tid < 192) {
        int nsub = tid / 24;
        int u = tid - nsub * 24;          // u = b*3+c
        int b = u / 3, c = u - b * 3;
        int n = n0 + nsub;
        const int* nb = nbr + n * 9;
        const float* Ar = a_lds + nsub * 81;
        float s[9];
#pragma unroll
        for (int t = 0; t < 9; t++) s[t] = 0.f;
#pragma unroll
        for (int k = 0; k < 9; k++) {
            float f = bf2f(Xin[nb[k] * 24 + u]);
#pragma unroll
            for (int t = 0; t < 9; t++) s[t] = fmaf(Ar[k * 9 + t], f, s[t]);
        }
        int col = nsub * 8 + b;
#pragma unroll
        for (int t = 0; t < 9; t++) S[col * KSTR + t * 3 + c] = (short)f2bf(s[t]);
    }
    __syncthreads();

    int lane = tid & 63, wv = tid >> 6, q = lane >> 4, cl = lane & 15;
    int colg = wv * 16 + cl;

    const bf16x8* wf = (const bf16x8*)Wp;
    f32x4 acc[MW];
#pragma unroll
    for (int m = 0; m < MW; m++) acc[m] = (f32x4){0.f, 0.f, 0.f, 0.f};
#pragma unroll
    for (int kt = 0; kt < KT; kt++) {
        bf16x8 bfr = *(const bf16x8*)&S[colg * KSTR + kt * 32 + q * 8];
#pragma unroll
        for (int m = 0; m < MW; m++) {
            const bf16x8* wg = wf + (m >> 1) * (KT * 128);
            bf16x8 am = wg[(kt * 4 + q) * 32 + cl + (m & 1) * 16];
            acc[m] = __builtin_amdgcn_mfma_f32_16x16x32_bf16(am, bfr, acc[m], 0, 0, 0);
        }
    }
    __syncthreads();

    float* Yf = (float*)Sraw;
    float* P2f = Yf + 64 * YSTR;
    int C = tile * 64 + colg;
#pragma unroll
    for (int m = 0; m < MW; m++) {
        f32x4 v;
#pragma unroll
        for (int i = 0; i < 4; i++) v[i] = acc[m][i] + bias[m * 16 + q * 4 + i];
        *(f32x4*)&Yf[colg * YSTR + m * 16 + q * 4] = v;
        uint2 pk;
        pk.x = cvtpk(v[0], v[1]);
        pk.y = cvtpk(v[2], v[3]);
        *(uint2*)&Yb[(size_t)C * OC + m * 16 + q * 4] = pk;
    }
    __syncthreads();
    {
        int o = tid & (OC - 1);
        int part = tid >> OSH;
        float s = 0.f, qq = 0.f;
#pragma unroll
        for (int i = 0; i < PCOLS; i++) {
            float y = Yf[(part * PCOLS + i) * YSTR + o];
            s += y;
            qq += y * y;
        }
        P2f[part * 2 * OC + o] = s;
        P2f[part * 2 * OC + OC + o] = qq;
    }
    __syncthreads();
    if (tid < 2 * OC) {
        double v = 0.0;
#pragma unroll
        for (int p = 0; p < PARTS; p++) v += (double)P2f[p * 2 * OC + tid];
        Part[(size_t)tid * NT_TILES + tile] = v;
    }
}

// ---------------- conv32: B-operand computed IN-REGISTER (no LDS S stage) ----------------
// Thread (q,cl) of wave wv owns col = wv*16+cl (node wv*2+(cl>>3), batch cl&7),
// channels 8q..8q+7 — exactly its MFMA B-fragment. Taps split 5/4 to bound live regs.
// LDS: a_lds + epilogue scratch only (~22KB) -> 5-6 blocks/CU; 3 barriers/tile.
template <int MW>   // MW = OC/16
__global__ __launch_bounds__(256, 5)
void conv32_kernel(const unsigned short* __restrict__ Xin,
                   const int* __restrict__ nbr,
                   const float* __restrict__ A,
                   const unsigned short* __restrict__ Wp,
                   const float* __restrict__ bias,
                   const float* __restrict__ bnsc,
                   const float* __restrict__ bnsh,
                   unsigned short* __restrict__ Yb,
                   double* __restrict__ Part) {
    constexpr int OC = MW * 16;
    constexpr int PARTS = 256 / OC;           // 8 / 4
    constexpr int PCOLS = 64 / PARTS;         // 8 / 16
    constexpr int OSH = (OC == 32) ? 5 : 6;
    constexpr int YSTR = OC + 4;
    __shared__ alignas(16) float Yf[64 * YSTR];
    __shared__ float P2f[PARTS * 2 * OC];
    __shared__ float a_lds[648];

    int tid = threadIdx.x;
    int tile = blockIdx.x;
    int n0 = tile * 8;
    int lane = tid & 63, wv = tid >> 6;
    int q = lane >> 4, cl = lane & 15;
    int nl = wv * 2 + (cl >> 3);              // local node 0..7
    int b = cl & 7;
    int colg = wv * 16 + cl;

    float4 sc0 = *(const float4*)&bnsc[8 * q];
    float4 sc1 = *(const float4*)&bnsc[8 * q + 4];
    float4 sh0 = *(const float4*)&bnsh[8 * q];
    float4 sh1 = *(const float4*)&bnsh[8 * q + 4];

    const uint4* X4 = (const uint4*)Xin;      // input row = 64B = 4 uint4
    uint4 fu[9];                              // 9 x 16B gathers: col j*8+b, ch 8q..8q+7
#pragma unroll
    for (int k = 0; k < 9; k++) {
        int j = nbr[(n0 + nl) * 9 + k];
        fu[k] = X4[(size_t)(j * 8 + b) * 4 + q];
    }
    for (int i = tid; i < 648; i += 256) a_lds[i] = A[(size_t)n0 * 81 + i];
    __syncthreads();                          // a_lds ready (gathers still in flight)

    const float* Ar = a_lds + nl * 81;
    const bf16x8* wf = (const bf16x8*)Wp;
    f32x4 acc[MW];
#pragma unroll
    for (int m = 0; m < MW; m++) acc[m] = (f32x4){0.f, 0.f, 0.f, 0.f};

    // ---- taps 0..4: accumulate, pack, MFMA (B-frag stays in registers) ----
    unsigned pk1[20];
    {
        float s[8][5];
#pragma unroll
        for (int c = 0; c < 8; c++)
#pragma unroll
            for (int t = 0; t < 5; t++) s[c][t] = 0.f;
#pragma unroll
        for (int k = 0; k < 9; k++) {
            float f0 = fmaxf(fmaf(bflo(fu[k].x), sc0.x, sh0.x), 0.f);
            float f1 = fmaxf(fmaf(bfhi(fu[k].x), sc0.y, sh0.y), 0.f);
            float f2 = fmaxf(fmaf(bflo(fu[k].y), sc0.z, sh0.z), 0.f);
            float f3 = fmaxf(fmaf(bfhi(fu[k].y), sc0.w, sh0.w), 0.f);
            float f4 = fmaxf(fmaf(bflo(fu[k].z), sc1.x, sh1.x), 0.f);
            float f5 = fmaxf(fmaf(bfhi(fu[k].z), sc1.y, sh1.y), 0.f);
            float f6 = fmaxf(fmaf(bflo(fu[k].w), sc1.z, sh1.z), 0.f);
            float f7 = fmaxf(fmaf(bfhi(fu[k].w), sc1.w, sh1.w), 0.f);
#pragma unroll
            for (int t = 0; t < 5; t++) {
                float a = Ar[k * 9 + t];
                s[0][t] = fmaf(a, f0, s[0][t]);
                s[1][t] = fmaf(a, f1, s[1][t]);
                s[2][t] = fmaf(a, f2, s[2][t]);
                s[3][t] = fmaf(a, f3, s[3][t]);
                s[4][t] = fmaf(a, f4, s[4][t]);
                s[5][t] = fmaf(a, f5, s[5][t]);
                s[6][t] = fmaf(a, f6, s[6][t]);
                s[7][t] = fmaf(a, f7, s[7][t]);
            }
        }
#pragma unroll
        for (int t = 0; t < 5; t++) {
            pk1[t * 4 + 0] = cvtpk(s[0][t], s[1][t]);
            pk1[t * 4 + 1] = cvtpk(s[2][t], s[3][t]);
            pk1[t * 4 + 2] = cvtpk(s[4][t], s[5][t]);
            pk1[t * 4 + 3] = cvtpk(s[6][t], s[7][t]);
        }
    }
#pragma unroll
    for (int kt = 0; kt < 5; kt++) {
        uint4 uu = {pk1[kt * 4 + 0], pk1[kt * 4 + 1], pk1[kt * 4 + 2], pk1[kt * 4 + 3]};
        bf16x8 bfr = __builtin_bit_cast(bf16x8, uu);
#pragma unroll
        for (int m = 0; m < MW; m++) {
            const bf16x8* wg = wf + (m >> 1) * (9 * 128);
            bf16x8 am = wg[(kt * 4 + q) * 32 + cl + (m & 1) * 16];
            acc[m] = __builtin_amdgcn_mfma_f32_16x16x32_bf16(am, bfr, acc[m], 0, 0, 0);
        }
    }

    // ---- taps 5..8: recompute unpack (fu still live), accumulate, pack, MFMA ----
    unsigned pk2[16];
    {
        float s[8][4];
#pragma unroll
        for (int c = 0; c < 8; c++)
#pragma unroll
            for (int t = 0; t < 4; t++) s[c][t] = 0.f;
#pragma unroll
        for (int k = 0; k < 9; k++) {
            float f0 = fmaxf(fmaf(bflo(fu[k].x), sc0.x, sh0.x), 0.f);
            float f1 = fmaxf(fmaf(bfhi(fu[k].x), sc0.y, sh0.y), 0.f);
            float f2 = fmaxf(fmaf(bflo(fu[k].y), sc0.z, sh0.z), 0.f);
            float f3 = fmaxf(fmaf(bfhi(fu[k].y), sc0.w, sh0.w), 0.f);
            float f4 = fmaxf(fmaf(bflo(fu[k].z), sc1.x, sh1.x), 0.f);
            float f5 = fmaxf(fmaf(bfhi(fu[k].z), sc1.y, sh1.y), 0.f);
            float f6 = fmaxf(fmaf(bflo(fu[k].w), sc1.z, sh1.z), 0.f);
            float f7 = fmaxf(fmaf(bfhi(fu[k].w), sc1.w, sh1.w), 0.f);
#pragma unroll
            for (int t = 0; t < 4; t++) {
                float a = Ar[k * 9 + 5 + t];
                s[0][t] = fmaf(a, f0, s[0][t]);
                s[1][t] = fmaf(a, f1, s[1][t]);
                s[2][t] = fmaf(a, f2, s[2][t]);
                s[3][t] = fmaf(a, f3, s[3][t]);
                s[4][t] = fmaf(a, f4, s[4][t]);
                s[5][t] = fmaf(a, f5, s[5][t]);
                s[6][t] = fmaf(a, f6, s[6][t]);
                s[7][t] = fmaf(a, f7, s[7][t]);
            }
        }
#pragma unroll
        for (int t = 0; t < 4; t++) {
            pk2[t * 4 + 0] = cvtpk(s[0][t], s[1][t]);
            pk2[t * 4 + 1] = cvtpk(s[2][t], s[3][t]);
            pk2[t * 4 + 2] = cvtpk(s[4][t], s[5][t]);
            pk2[t * 4 + 3] = cvtpk(s[6][t], s[7][t]);
        }
    }
#pragma unroll
    for (int kt = 5; kt < 9; kt++) {
        int u0 = (kt - 5) * 4;
        uint4 uu = {pk2[u0 + 0], pk2[u0 + 1], pk2[u0 + 2], pk2[u0 + 3]};
        bf16x8 bfr = __builtin_bit_cast(bf16x8, uu);
#pragma unroll
        for (int m = 0; m < MW; m++) {
            const bf16x8* wg = wf + (m >> 1) * (9 * 128);
            bf16x8 am = wg[(kt * 4 + q) * 32 + cl + (m & 1) * 16];
            acc[m] = __builtin_amdgcn_mfma_f32_16x16x32_bf16(am, bfr, acc[m], 0, 0, 0);
        }
    }

    // ---- epilogue: bias, Yb store, BN partials via LDS ----
    int C = tile * 64 + colg;
#pragma unroll
    for (int m = 0; m < MW; m++) {
        f32x4 v;
#pragma unroll
        for (int i = 0; i < 4; i++) v[i] = acc[m][i] + bias[m * 16 + q * 4 + i];
        *(f32x4*)&Yf[colg * YSTR + m * 16 + q * 4] = v;
        uint2 pk;
        pk.x = cvtpk(v[0], v[1]);
        pk.y = cvtpk(v[2], v[3]);
        *(uint2*)&Yb[(size_t)C * OC + m * 16 + q * 4] = pk;
    }
    __syncthreads();
    {
        int o = tid & (OC - 1);
        int part = tid >> OSH;
        float s = 0.f, qq = 0.f;
#pragma unroll
        for (int i = 0; i < PCOLS; i++) {
            float y = Yf[(part * PCOLS + i) * YSTR + o];
            s += y;
            qq += y * y;
        }
        P2f[part * 2 * OC + o] = s;
        P2f[part * 2 * OC + OC + o] = qq;
    }
    __syncthreads();
    if (tid < 2 * OC) {
        double v = 0.0;
#pragma unroll
        for (int p = 0; p < PARTS; p++) v += (double)P2f[p * 2 * OC + tid];
        Part[(size_t)tid * NT_TILES + tile] = v;
    }
}

// ---------------- BN reduce+finalize: one block per channel ----------------
__global__ __launch_bounds__(256, 8)
void bn_reduce(const double* __restrict__ Part,
               const float* __restrict__ g, const float* __restrict__ be,
               float* __restrict__ sc, float* __restrict__ sh, int OC) {
    int o = blockIdx.x;
    int tid = threadIdx.x;
    const double* ps = Part + (size_t)o * NT_TILES;
    const double* pq = Part + (size_t)(OC + o) * NT_TILES;
    double s = 0.0, q = 0.0;
    for (int t = tid; t < NT_TILES; t += 256) {
        s += ps[t];
        q += pq[t];
    }
#pragma unroll
    for (int d = 1; d < 64; d <<= 1) {
        s += __shfl_xor(s, d);
        q += __shfl_xor(q, d);
    }
    __shared__ double red[8];
    int wv = tid >> 6;
    if ((tid & 63) == 0) { red[wv] = s; red[4 + wv] = q; }
    __syncthreads();
    if (tid == 0) {
        double S = red[0] + red[1] + red[2] + red[3];
        double Q = red[4] + red[5] + red[6] + red[7];
        double cnt = (double)N2C * 8.0;
        double mean = S / cnt;
        double var = Q / cnt - mean * mean;
        double rs = 1.0 / sqrt(var + 1e-5);
        double scale = (double)g[o] * rs;
        sc[o] = (float)scale;
        sh[o] = (float)((double)be[o] - mean * scale);
    }
}

// ---------------- pool: 2 m per 256-thr block; thread owns a channel pair ----------------
__global__ __launch_bounds__(256, 8)
void pool_kernel(const unsigned short* __restrict__ Y3, const int* __restrict__ pidx,
                 const float* __restrict__ sc, const float* __restrict__ sh,
                 float* __restrict__ out) {
    int m0 = blockIdx.x * 2;
    int tid = threadIdx.x;      // b*32 + o2  (o2 = channel pair)
    int o2 = tid & 31;
    int b = tid >> 5;
    float s0 = sc[2 * o2], h0 = sh[2 * o2];
    float s1 = sc[2 * o2 + 1], h1 = sh[2 * o2 + 1];
    const unsigned* Y3u = (const unsigned*)Y3;
    int j0[9], j1[9];
#pragma unroll
    for (int k = 0; k < 9; k++) {
        j0[k] = pidx[m0 * 9 + k];
        j1[k] = pidx[m0 * 9 + 9 + k];
    }
    unsigned u0[9], u1[9];                      // all 18 gathers in flight
#pragma unroll
    for (int k = 0; k < 9; k++) u0[k] = Y3u[(size_t)j0[k] * 256 + tid];
#pragma unroll
    for (int k = 0; k < 9; k++) u1[k] = Y3u[(size_t)j1[k] * 256 + tid];
    float a0 = 0.f, a1 = 0.f, c0 = 0.f, c1 = 0.f;
#pragma unroll
    for (int k = 0; k < 9; k++) {
        a0 = fmaxf(a0, fmaf(bflo(u0[k]), s0, h0));
        a1 = fmaxf(a1, fmaf(bfhi(u0[k]), s1, h1));
        c0 = fmaxf(c0, fmaf(bflo(u1[k]), s0, h0));
        c1 = fmaxf(c1, fmaf(bfhi(u1[k]), s1, h1));
    }
    float2 r0 = {a0, c0};       // channel 2*o2,   m0 / m0+1
    float2 r1 = {a1, c1};       // channel 2*o2+1, m0 / m0+1
    *(float2*)(out + (size_t)(b * 64 + 2 * o2) * 3136 + m0) = r0;
    *(float2*)(out + (size_t)(b * 64 + 2 * o2 + 1) * 3136 + m0) = r1;
}

extern "C" void kernel_launch(void* const* d_in, const int* in_sizes, int n_in,
                              void* d_out, int out_size, void* d_ws, size_t ws_size,
                              hipStream_t stream) {
    const float* x    = (const float*)d_in[0];
    const int*   nbr1 = (const int*)d_in[1];
    const float* off1 = (const float*)d_in[2];
    const int*   nbr2 = (const int*)d_in[3];
    const float* off2 = (const float*)d_in[4];
    const int*   pidx = (const int*)d_in[5];
    const float* Wh   = (const float*)d_in[6];
    const float* bh   = (const float*)d_in[7];
    const float* Wo   = (const float*)d_in[8];
    const float* bo   = (const float*)d_in[9];
    const float* W1   = (const float*)d_in[10];
    const float* b1   = (const float*)d_in[11];
    const float* W2   = (const float*)d_in[12];
    const float* b2   = (const float*)d_in[13];
    const float* W3   = (const float*)d_in[14];
    const float* b3   = (const float*)d_in[15];
    const float* g1   = (const float*)d_in[16];
    const float* be1  = (const float*)d_in[17];
    const float* g2   = (const float*)d_in[18];
    const float* be2  = (const float*)d_in[19];
    const float* g3   = (const float*)d_in[20];
    const float* be3  = (const float*)d_in[21];

    char* ws = (char*)d_ws;
    size_t off = 0;
    auto alloc = [&](size_t bytes) -> void* {
        void* p = ws + off;
        off += (bytes + 255) & ~(size_t)255;
        return p;
    };
    unsigned short* X0b = (unsigned short*)alloc((size_t)N1C * 24 * 2);   // 2.4MB
    float* A1 = (float*)alloc((size_t)N2C * 81 * 4);                      // 4.1MB
    float* A2 = (float*)alloc((size_t)N2C * 81 * 4);                      // 4.1MB
    unsigned short* Y1b = (unsigned short*)alloc((size_t)N2C * 8 * 32 * 2);  // 6.4MB
    unsigned short* Y2b = (unsigned short*)alloc((size_t)N2C * 8 * 32 * 2);  // 6.4MB
    unsigned short* Y3b = (unsigned short*)alloc((size_t)N2C * 8 * 64 * 2);  // 12.8MB
    unsigned short* W1p = (unsigned short*)alloc(32 * 32 * 2);
    unsigned short* W2p = (unsigned short*)alloc(32 * 288 * 2);
    unsigned short* W3p = (unsigned short*)alloc(64 * 288 * 2);
    double* Part  = (double*)alloc((size_t)NT_TILES * 128 * 8);           // 1.6MB
    float*  scbuf = (float*)alloc(256 * 4);

    float* sc1 = scbuf;       float* sh1 = scbuf + 32;
    float* sc2 = scbuf + 64;  float* sh2 = scbuf + 96;
    float* sc3 = scbuf + 128; float* sh3 = scbuf + 192;

    prologue_kernel<<<TRB + MLB + PWB, 256, 0, stream>>>(
        x, X0b, off1, off2, Wh, bh, Wo, bo, A1, A2, W1, W2, W3, W1p, W2p, W3p);

    conv_kernel<3, 2, false><<<NT_TILES, 256, 0, stream>>>(
        X0b, nbr1, A1, W1p, b1, nullptr, nullptr, Y1b, Part);
    bn_reduce<<<32, 256, 0, stream>>>(Part, g1, be1, sc1, sh1, 32);

    conv32_kernel<2><<<NT_TILES, 256, 0, stream>>>(
        Y1b, nbr2, A2, W2p, b2, sc1, sh1, Y2b, Part);
    bn_reduce<<<32, 256, 0, stream>>>(Part, g2, be2, sc2, sh2, 32);

    conv32_kernel<4><<<NT_TILES, 256, 0, stream>>>(
        Y2b, nbr2, A2, W3p, b3, sc2, sh2, Y3b, Part);
    bn_reduce<<<64, 256, 0, stream>>>(Part, g3, be3, sc3, sh3, 64);

    pool_kernel<<<N3C / 2, 256, 0, stream>>>(Y3b, pidx, sc3, sh3, (float*)d_out);
}

// Round 10
// 191.956 us; speedup vs baseline: 1.5731x; 1.5731x over previous
//
#include <hip/hip_runtime.h>
#include <math.h>

#define N1C 50176
#define N2C 12544
#define N3C 3136
#define NT_TILES (N2C * 8 / 64)   // 1568 conv tiles (64 cols each)

typedef __attribute__((ext_vector_type(8))) short bf16x8;
typedef __attribute__((ext_vector_type(4))) float f32x4;

__device__ __forceinline__ unsigned short f2bf(float f) {
    unsigned u = __builtin_bit_cast(unsigned, f);
    u += 0x7fffu + ((u >> 16) & 1u);
    return (unsigned short)(u >> 16);
}
// single-instruction RNE pack of 2 f32 -> 2 bf16
__device__ __forceinline__ unsigned cvtpk(float lo, float hi) {
    unsigned r;
    asm("v_cvt_pk_bf16_f32 %0, %1, %2" : "=v"(r) : "v"(lo), "v"(hi));
    return r;
}
__device__ __forceinline__ float bf2f(unsigned short u) {
    return __builtin_bit_cast(float, (unsigned)u << 16);
}
__device__ __forceinline__ float bflo(unsigned u) {
    return __builtin_bit_cast(float, u << 16);
}
__device__ __forceinline__ float bfhi(unsigned u) {
    return __builtin_bit_cast(float, u & 0xffff0000u);
}

// ---------------- fused prologue: transpose | mlp(off1+off2) | pad_w(W1,W2,W3) ----------------
#define TRB (N1C / 64)            // 784
#define MLB (2 * N2C * 9 / 256)   // 882  (first 441 -> A1, rest -> A2; boundary block-aligned)
#define PWB 112                   // (1024+9216+18432)/256

__device__ __forceinline__ void pad_one(int i, const float* __restrict__ W,
                                        unsigned short* __restrict__ Wp,
                                        int OC, int CIN, int KT) {
    int j = i & 7;
    int op = (i >> 3) & 31;
    int q = (i >> 8) & 3;
    int kt = (i >> 10) % KT;
    int g = i / (KT * 1024);
    int kp = kt * 32 + q * 8 + j;
    int t = kp / CIN, c = kp - t * CIN;
    int o = g * 32 + op;
    float v = (t < 9 && o < OC) ? W[(o * CIN + c) * 9 + t] : 0.f;
    Wp[i] = f2bf(v);
}

__global__ void prologue_kernel(const float* __restrict__ x, unsigned short* __restrict__ X0,
                                const float* __restrict__ off1, const float* __restrict__ off2,
                                const float* __restrict__ Wh, const float* __restrict__ bh,
                                const float* __restrict__ Wo, const float* __restrict__ bo,
                                float* __restrict__ A1, float* __restrict__ A2,
                                const float* __restrict__ W1, const float* __restrict__ W2,
                                const float* __restrict__ W3,
                                unsigned short* __restrict__ W1p, unsigned short* __restrict__ W2p,
                                unsigned short* __restrict__ W3p) {
    __shared__ float U[2304];     // transpose tile (1600 used) | A staging (2304)
    int blk = blockIdx.x;
    int tid = threadIdx.x;
    if (blk < TRB) {
        int n0 = blk * 64;
        for (int r = tid; r < 24 * 64; r += 256) {
            int cb = r >> 6;
            int nn = r & 63;
            U[nn * 25 + cb] = x[cb * N1C + n0 + nn];
        }
        __syncthreads();
        for (int w = tid; w < 64 * 24; w += 256) {
            int nn = w / 24;
            int u = w - nn * 24;
            X0[(n0 + nn) * 24 + u] = f2bf(U[nn * 25 + u]);
        }
    } else if (blk < TRB + MLB) {
        int bi = blk - TRB;
        int idx = bi * 256 + tid;
        const float* offp;
        if (idx < N2C * 9) offp = off1 + idx * 2;
        else offp = off2 + (idx - N2C * 9) * 2;
        float o0 = offp[0], o1 = offp[1];
        float out[9];
#pragma unroll
        for (int t = 0; t < 9; t++) out[t] = bo[t];
#pragma unroll
        for (int h = 0; h < 32; h++) {
            float hv = fmaxf(o0 * Wh[h] + o1 * Wh[32 + h] + bh[h], 0.f);
#pragma unroll
            for (int t = 0; t < 9; t++) out[t] += hv * Wo[h * 9 + t];
        }
#pragma unroll
        for (int t = 0; t < 9; t++) U[tid * 9 + t] = out[t];   // stride 9: conflict-free
        __syncthreads();
        float* dst = (bi < 441) ? (A1 + (size_t)bi * 2304)
                                : (A2 + (size_t)(bi - 441) * 2304);
        for (int i = tid; i < 2304; i += 256) dst[i] = U[i];   // coalesced
    } else {
        int i = (blk - TRB - MLB) * 256 + tid;
        if (i < 1024) pad_one(i, W1, W1p, 32, 3, 1);
        else if (i < 10240) pad_one(i - 1024, W2, W2p, 32, 32, 9);
        else pad_one(i - 10240, W3, W3p, 64, 32, 9);
    }
}

// ---------------- conv1: CIN=3 gather+weight -> LDS S -> MFMA (verified round-7 form) ----------------
template <int CIN, int MW, bool HAS_BN>   // instantiated with CIN=3 only
__global__ __launch_bounds__(256, 4)
void conv_kernel(const unsigned short* __restrict__ Xin,
                 const int* __restrict__ nbr,
                 const float* __restrict__ A,
                 const unsigned short* __restrict__ Wp,
                 const float* __restrict__ bias,
                 const float* __restrict__ bnsc,
                 const float* __restrict__ bnsh,
                 unsigned short* __restrict__ Yb,
                 double* __restrict__ Part) {
    constexpr int OC = MW * 16;
    constexpr int KREAL = 9 * CIN;
    constexpr int KROW = (KREAL + 31) & ~31;
    constexpr int KT = KROW / 32;
    constexpr int KSTR = KROW + 8;
    constexpr int PARTS = 256 / OC;
    constexpr int PCOLS = 64 / PARTS;
    constexpr int OSH = (OC == 32) ? 5 : 6;
    constexpr int YSTR = OC + 4;
    constexpr int SB1 = 64 * KSTR * 2;
    constexpr int SB2 = 64 * YSTR * 4 + PARTS * 2 * OC * 4;
    constexpr int SBYTES = SB1 > SB2 ? SB1 : SB2;
    __shared__ alignas(16) char Sraw[SBYTES];
    __shared__ float a_lds[8 * 81];
    short* S = (short*)Sraw;

    int tid = threadIdx.x;
    int tile = blockIdx.x;
    int n0 = tile * 8;

    for (int i = tid; i < 64 * KSTR; i += 256) S[i] = 0;   // zero pad slots
    for (int i = tid; i < 648; i += 256) a_lds[i] = A[(size_t)n0 * 81 + i];
    __syncthreads();
    if (tid < 192) {
        int nsub = tid / 24;
        int u = tid - nsub * 24;          // u = b*3+c
        int b = u / 3, c = u - b * 3;
        int n = n0 + nsub;
        const int* nb = nbr + n * 9;
        const float* Ar = a_lds + nsub * 81;
        float s[9];
#pragma unroll
        for (int t = 0; t < 9; t++) s[t] = 0.f;
#pragma unroll
        for (int k = 0; k < 9; k++) {
            float f = bf2f(Xin[nb[k] * 24 + u]);
#pragma unroll
            for (int t = 0; t < 9; t++) s[t] = fmaf(Ar[k * 9 + t], f, s[t]);
        }
        int col = nsub * 8 + b;
#pragma unroll
        for (int t = 0; t < 9; t++) S[col * KSTR + t * 3 + c] = (short)f2bf(s[t]);
    }
    __syncthreads();

    int lane = tid & 63, wv = tid >> 6, q = lane >> 4, cl = lane & 15;
    int colg = wv * 16 + cl;

    const bf16x8* wf = (const bf16x8*)Wp;
    f32x4 acc[MW];
#pragma unroll
    for (int m = 0; m < MW; m++) acc[m] = (f32x4){0.f, 0.f, 0.f, 0.f};
#pragma unroll
    for (int kt = 0; kt < KT; kt++) {
        bf16x8 bfr = *(const bf16x8*)&S[colg * KSTR + kt * 32 + q * 8];
#pragma unroll
        for (int m = 0; m < MW; m++) {
            const bf16x8* wg = wf + (m >> 1) * (KT * 128);
            bf16x8 am = wg[(kt * 4 + q) * 32 + cl + (m & 1) * 16];
            acc[m] = __builtin_amdgcn_mfma_f32_16x16x32_bf16(am, bfr, acc[m], 0, 0, 0);
        }
    }
    __syncthreads();

    float* Yf = (float*)Sraw;
    float* P2f = Yf + 64 * YSTR;
    int C = tile * 64 + colg;
#pragma unroll
    for (int m = 0; m < MW; m++) {
        f32x4 v;
#pragma unroll
        for (int i = 0; i < 4; i++) v[i] = acc[m][i] + bias[m * 16 + q * 4 + i];
        *(f32x4*)&Yf[colg * YSTR + m * 16 + q * 4] = v;
        uint2 pk;
        pk.x = cvtpk(v[0], v[1]);
        pk.y = cvtpk(v[2], v[3]);
        *(uint2*)&Yb[(size_t)C * OC + m * 16 + q * 4] = pk;
    }
    __syncthreads();
    {
        int o = tid & (OC - 1);
        int part = tid >> OSH;
        float s = 0.f, qq = 0.f;
#pragma unroll
        for (int i = 0; i < PCOLS; i++) {
            float y = Yf[(part * PCOLS + i) * YSTR + o];
            s += y;
            qq += y * y;
        }
        P2f[part * 2 * OC + o] = s;
        P2f[part * 2 * OC + OC + o] = qq;
    }
    __syncthreads();
    if (tid < 2 * OC) {
        double v = 0.0;
#pragma unroll
        for (int p = 0; p < PARTS; p++) v += (double)P2f[p * 2 * OC + tid];
        Part[(size_t)tid * NT_TILES + tile] = v;
    }
}

// ---------------- conv32: round-7 dataflow, WAVE-INDEPENDENT (1 barrier/tile) ----------------
// S staging is wave-local (wave wv writes AND reads cols 16wv..16wv+15), a_lds slices are
// wave-local, BN partials via 16-lane f32 shuffle parked in the wave's own consumed a_lds
// slice. DS ops are in-order per wave; compiler lgkmcnt covers same-wave LDS RAW.
template <int MW>   // MW = OC/16
__global__ __launch_bounds__(256, 4)
void conv32_kernel(const unsigned short* __restrict__ Xin,
                   const int* __restrict__ nbr,
                   const float* __restrict__ A,
                   const unsigned short* __restrict__ Wp,
                   const float* __restrict__ bias,
                   const float* __restrict__ bnsc,
                   const float* __restrict__ bnsh,
                   unsigned short* __restrict__ Yb,
                   double* __restrict__ Part) {
    constexpr int OC = MW * 16;
    constexpr int KSTR = 296;                 // 288 + 8 pad (uint2-safe, bank-spread)
    __shared__ alignas(16) short S[64 * KSTR];   // 37888 B
    __shared__ float a_lds[648];              // 4 wave slices x 162 f32 (A rows, then BN partials)

    int tid = threadIdx.x;
    int tile = blockIdx.x;
    int n0 = tile * 8;
    int wv = __builtin_amdgcn_readfirstlane(tid >> 6);    // wave id (uniform)
    int lane = tid & 63;
    int b = lane >> 3, c4 = lane & 7;
    int q = lane >> 4, cl = lane & 15;
    int colg = wv * 16 + cl;

    float4 scv = *(const float4*)&bnsc[4 * c4];
    float4 shv = *(const float4*)&bnsh[4 * c4];
    const uint2* Xd = (const uint2*)Xin;      // node row = 64 uint2 (512B)

    // ---- 18 gathers in flight upfront (wave-uniform nbr base -> s_load) ----
    uint2 fu[18];
#pragma unroll
    for (int gg = 0; gg < 2; gg++)
#pragma unroll
        for (int k = 0; k < 9; k++) {
            int j = nbr[(n0 + wv * 2 + gg) * 9 + k];
            fu[gg * 9 + k] = Xd[(size_t)j * 64 + lane];
        }
    // ---- wave-local A stage: this wave's 2 rows (162 f32) into its own slice ----
    {
        int base = 162 * wv;
        const float* Ag = A + (size_t)n0 * 81 + base;
        a_lds[base + lane] = Ag[lane];
        a_lds[base + 64 + lane] = Ag[64 + lane];
        if (lane < 34) a_lds[base + 128 + lane] = Ag[128 + lane];
    }

    // ---- phase A: weighted sums -> S (own 16 cols; no barrier) ----
#pragma unroll
    for (int gg = 0; gg < 2; gg++) {
        const float* Ar = a_lds + 162 * wv + 81 * gg;
        float s0[9], s1[9], s2[9], s3[9];
#pragma unroll
        for (int t = 0; t < 9; t++) { s0[t] = 0.f; s1[t] = 0.f; s2[t] = 0.f; s3[t] = 0.f; }
#pragma unroll
        for (int k = 0; k < 9; k++) {
            uint2 u = fu[gg * 9 + k];
            float f0 = fmaxf(fmaf(bflo(u.x), scv.x, shv.x), 0.f);
            float f1 = fmaxf(fmaf(bfhi(u.x), scv.y, shv.y), 0.f);
            float f2 = fmaxf(fmaf(bflo(u.y), scv.z, shv.z), 0.f);
            float f3 = fmaxf(fmaf(bfhi(u.y), scv.w, shv.w), 0.f);
#pragma unroll
            for (int t = 0; t < 9; t++) {
                float a = Ar[k * 9 + t];
                s0[t] = fmaf(a, f0, s0[t]);
                s1[t] = fmaf(a, f1, s1[t]);
                s2[t] = fmaf(a, f2, s2[t]);
                s3[t] = fmaf(a, f3, s3[t]);
            }
        }
        int col = (wv * 2 + gg) * 8 + b;
        uint2* Srow = (uint2*)&S[col * KSTR];
#pragma unroll
        for (int t = 0; t < 9; t++) {
            uint2 pk;
            pk.x = cvtpk(s0[t], s1[t]);
            pk.y = cvtpk(s2[t], s3[t]);
            Srow[t * 8 + c4] = pk;              // short off = t*32 + 4*c4
        }
    }

    // ---- phase B: MFMA on own 16 cols (same-wave LDS RAW; no barrier) ----
    const bf16x8* wf = (const bf16x8*)Wp;
    f32x4 acc[MW];
#pragma unroll
    for (int m = 0; m < MW; m++) acc[m] = (f32x4){0.f, 0.f, 0.f, 0.f};
#pragma unroll
    for (int kt = 0; kt < 9; kt++) {
        bf16x8 bfr = *(const bf16x8*)&S[colg * KSTR + kt * 32 + q * 8];
#pragma unroll
        for (int m = 0; m < MW; m++) {
            const bf16x8* wg = wf + (m >> 1) * (9 * 128);
            bf16x8 am = wg[(kt * 4 + q) * 32 + cl + (m & 1) * 16];
            acc[m] = __builtin_amdgcn_mfma_f32_16x16x32_bf16(am, bfr, acc[m], 0, 0, 0);
        }
    }

    // ---- epilogue: Yb from registers; BN partials via 16-lane shuffle (wave-local) ----
    int C = tile * 64 + colg;
    float yv[4 * MW];
#pragma unroll
    for (int m = 0; m < MW; m++) {
#pragma unroll
        for (int i = 0; i < 4; i++) yv[m * 4 + i] = acc[m][i] + bias[m * 16 + q * 4 + i];
        uint2 pk;
        pk.x = cvtpk(yv[m * 4 + 0], yv[m * 4 + 1]);
        pk.y = cvtpk(yv[m * 4 + 2], yv[m * 4 + 3]);
        *(uint2*)&Yb[(size_t)C * OC + m * 16 + q * 4] = pk;
    }
    float* P2w = a_lds + 162 * wv;            // reuse own consumed A slice (2*OC <= 128 < 162)
#pragma unroll
    for (int r = 0; r < 4 * MW; r++) {
        float ps = yv[r];
        float pq = yv[r] * yv[r];
#pragma unroll
        for (int d = 1; d < 16; d <<= 1) {    // reduce over cl within q-group
            ps += __shfl_xor(ps, d);
            pq += __shfl_xor(pq, d);
        }
        if (cl == 0) {
            int o = (r >> 2) * 16 + q * 4 + (r & 3);
            P2w[o] = ps;
            P2w[OC + o] = pq;
        }
    }
    __syncthreads();                          // the ONLY block barrier
    if (tid < 2 * OC) {
        double v = (double)a_lds[tid] + (double)a_lds[162 + tid] +
                   (double)a_lds[324 + tid] + (double)a_lds[486 + tid];
        Part[(size_t)tid * NT_TILES + tile] = v;   // transposed: coalesced in bn_reduce
    }
}

// ---------------- BN reduce+finalize: one block per channel ----------------
__global__ __launch_bounds__(256, 8)
void bn_reduce(const double* __restrict__ Part,
               const float* __restrict__ g, const float* __restrict__ be,
               float* __restrict__ sc, float* __restrict__ sh, int OC) {
    int o = blockIdx.x;
    int tid = threadIdx.x;
    const double* ps = Part + (size_t)o * NT_TILES;
    const double* pq = Part + (size_t)(OC + o) * NT_TILES;
    double s = 0.0, q = 0.0;
    for (int t = tid; t < NT_TILES; t += 256) {
        s += ps[t];
        q += pq[t];
    }
#pragma unroll
    for (int d = 1; d < 64; d <<= 1) {
        s += __shfl_xor(s, d);
        q += __shfl_xor(q, d);
    }
    __shared__ double red[8];
    int wv = tid >> 6;
    if ((tid & 63) == 0) { red[wv] = s; red[4 + wv] = q; }
    __syncthreads();
    if (tid == 0) {
        double S = red[0] + red[1] + red[2] + red[3];
        double Q = red[4] + red[5] + red[6] + red[7];
        double cnt = (double)N2C * 8.0;
        double mean = S / cnt;
        double var = Q / cnt - mean * mean;
        double rs = 1.0 / sqrt(var + 1e-5);
        double scale = (double)g[o] * rs;
        sc[o] = (float)scale;
        sh[o] = (float)((double)be[o] - mean * scale);
    }
}

// ---------------- pool: 2 m per 256-thr block; thread owns a channel pair ----------------
__global__ __launch_bounds__(256, 8)
void pool_kernel(const unsigned short* __restrict__ Y3, const int* __restrict__ pidx,
                 const float* __restrict__ sc, const float* __restrict__ sh,
                 float* __restrict__ out) {
    int m0 = blockIdx.x * 2;
    int tid = threadIdx.x;      // b*32 + o2  (o2 = channel pair)
    int o2 = tid & 31;
    int b = tid >> 5;
    float s0 = sc[2 * o2], h0 = sh[2 * o2];
    float s1 = sc[2 * o2 + 1], h1 = sh[2 * o2 + 1];
    const unsigned* Y3u = (const unsigned*)Y3;
    int j0[9], j1[9];
#pragma unroll
    for (int k = 0; k < 9; k++) {
        j0[k] = pidx[m0 * 9 + k];
        j1[k] = pidx[m0 * 9 + 9 + k];
    }
    unsigned u0[9], u1[9];                      // all 18 gathers in flight
#pragma unroll
    for (int k = 0; k < 9; k++) u0[k] = Y3u[(size_t)j0[k] * 256 + tid];
#pragma unroll
    for (int k = 0; k < 9; k++) u1[k] = Y3u[(size_t)j1[k] * 256 + tid];
    float a0 = 0.f, a1 = 0.f, c0 = 0.f, c1 = 0.f;
#pragma unroll
    for (int k = 0; k < 9; k++) {
        a0 = fmaxf(a0, fmaf(bflo(u0[k]), s0, h0));
        a1 = fmaxf(a1, fmaf(bfhi(u0[k]), s1, h1));
        c0 = fmaxf(c0, fmaf(bflo(u1[k]), s0, h0));
        c1 = fmaxf(c1, fmaf(bfhi(u1[k]), s1, h1));
    }
    float2 r0 = {a0, c0};       // channel 2*o2,   m0 / m0+1
    float2 r1 = {a1, c1};       // channel 2*o2+1, m0 / m0+1
    *(float2*)(out + (size_t)(b * 64 + 2 * o2) * 3136 + m0) = r0;
    *(float2*)(out + (size_t)(b * 64 + 2 * o2 + 1) * 3136 + m0) = r1;
}

extern "C" void kernel_launch(void* const* d_in, const int* in_sizes, int n_in,
                              void* d_out, int out_size, void* d_ws, size_t ws_size,
                              hipStream_t stream) {
    const float* x    = (const float*)d_in[0];
    const int*   nbr1 = (const int*)d_in[1];
    const float* off1 = (const float*)d_in[2];
    const int*   nbr2 = (const int*)d_in[3];
    const float* off2 = (const float*)d_in[4];
    const int*   pidx = (const int*)d_in[5];
    const float* Wh   = (const float*)d_in[6];
    const float* bh   = (const float*)d_in[7];
    const float* Wo   = (const float*)d_in[8];
    const float* bo   = (const float*)d_in[9];
    const float* W1   = (const float*)d_in[10];
    const float* b1   = (const float*)d_in[11];
    const float* W2   = (const float*)d_in[12];
    const float* b2   = (const float*)d_in[13];
    const float* W3   = (const float*)d_in[14];
    const float* b3   = (const float*)d_in[15];
    const float* g1   = (const float*)d_in[16];
    const float* be1  = (const float*)d_in[17];
    const float* g2   = (const float*)d_in[18];
    const float* be2  = (const float*)d_in[19];
    const float* g3   = (const float*)d_in[20];
    const float* be3  = (const float*)d_in[21];

    char* ws = (char*)d_ws;
    size_t off = 0;
    auto alloc = [&](size_t bytes) -> void* {
        void* p = ws + off;
        off += (bytes + 255) & ~(size_t)255;
        return p;
    };
    unsigned short* X0b = (unsigned short*)alloc((size_t)N1C * 24 * 2);   // 2.4MB
    float* A1 = (float*)alloc((size_t)N2C * 81 * 4);                      // 4.1MB
    float* A2 = (float*)alloc((size_t)N2C * 81 * 4);                      // 4.1MB
    unsigned short* Y1b = (unsigned short*)alloc((size_t)N2C * 8 * 32 * 2);  // 6.4MB
    unsigned short* Y2b = (unsigned short*)alloc((size_t)N2C * 8 * 32 * 2);  // 6.4MB
    unsigned short* Y3b = (unsigned short*)alloc((size_t)N2C * 8 * 64 * 2);  // 12.8MB
    unsigned short* W1p = (unsigned short*)alloc(32 * 32 * 2);
    unsigned short* W2p = (unsigned short*)alloc(32 * 288 * 2);
    unsigned short* W3p = (unsigned short*)alloc(64 * 288 * 2);
    double* Part  = (double*)alloc((size_t)NT_TILES * 128 * 8);           // 1.6MB
    float*  scbuf = (float*)alloc(256 * 4);

    float* sc1 = scbuf;       float* sh1 = scbuf + 32;
    float* sc2 = scbuf + 64;  float* sh2 = scbuf + 96;
    float* sc3 = scbuf + 128; float* sh3 = scbuf + 192;

    prologue_kernel<<<TRB + MLB + PWB, 256, 0, stream>>>(
        x, X0b, off1, off2, Wh, bh, Wo, bo, A1, A2, W1, W2, W3, W1p, W2p, W3p);

    conv_kernel<3, 2, false><<<NT_TILES, 256, 0, stream>>>(
        X0b, nbr1, A1, W1p, b1, nullptr, nullptr, Y1b, Part);
    bn_reduce<<<32, 256, 0, stream>>>(Part, g1, be1, sc1, sh1, 32);

    conv32_kernel<2><<<NT_TILES, 256, 0, stream>>>(
        Y1b, nbr2, A2, W2p, b2, sc1, sh1, Y2b, Part);
    bn_reduce<<<32, 256, 0, stream>>>(Part, g2, be2, sc2, sh2, 32);

    conv32_kernel<4><<<NT_TILES, 256, 0, stream>>>(
        Y2b, nbr2, A2, W3p, b3, sc2, sh2, Y3b, Part);
    bn_reduce<<<64, 256, 0, stream>>>(Part, g3, be3, sc3, sh3, 64);

    pool_kernel<<<N3C / 2, 256, 0, stream>>>(Y3b, pidx, sc3, sh3, (float*)d_out);
}

// Round 11
// 190.007 us; speedup vs baseline: 1.5893x; 1.0103x over previous
//
#include <hip/hip_runtime.h>
#include <math.h>

#define N1C 50176
#define N2C 12544
#define N3C 3136
#define NT_TILES (N2C * 8 / 64)   // 1568 conv tiles (64 cols each)

typedef __attribute__((ext_vector_type(8))) short bf16x8;
typedef __attribute__((ext_vector_type(4))) float f32x4;

__device__ __forceinline__ unsigned short f2bf(float f) {
    unsigned u = __builtin_bit_cast(unsigned, f);
    u += 0x7fffu + ((u >> 16) & 1u);
    return (unsigned short)(u >> 16);
}
// single-instruction RNE pack of 2 f32 -> 2 bf16
__device__ __forceinline__ unsigned cvtpk(float lo, float hi) {
    unsigned r;
    asm("v_cvt_pk_bf16_f32 %0, %1, %2" : "=v"(r) : "v"(lo), "v"(hi));
    return r;
}
__device__ __forceinline__ float bf2f(unsigned short u) {
    return __builtin_bit_cast(float, (unsigned)u << 16);
}
__device__ __forceinline__ float bflo(unsigned u) {
    return __builtin_bit_cast(float, u << 16);
}
__device__ __forceinline__ float bfhi(unsigned u) {
    return __builtin_bit_cast(float, u & 0xffff0000u);
}

// ---------------- fused prologue: transpose | mlp(off1+off2) | pad_w(W1,W2,W3) ----------------
#define TRB (N1C / 64)            // 784
#define MLB (2 * N2C * 9 / 256)   // 882  (first 441 -> A1, rest -> A2; boundary block-aligned)
#define PWB 112                   // (1024+9216+18432)/256

__device__ __forceinline__ void pad_one(int i, const float* __restrict__ W,
                                        unsigned short* __restrict__ Wp,
                                        int OC, int CIN, int KT) {
    int j = i & 7;
    int op = (i >> 3) & 31;
    int q = (i >> 8) & 3;
    int kt = (i >> 10) % KT;
    int g = i / (KT * 1024);
    int kp = kt * 32 + q * 8 + j;
    int t = kp / CIN, c = kp - t * CIN;
    int o = g * 32 + op;
    float v = (t < 9 && o < OC) ? W[(o * CIN + c) * 9 + t] : 0.f;
    Wp[i] = f2bf(v);
}

__global__ void prologue_kernel(const float* __restrict__ x, unsigned short* __restrict__ X0,
                                const float* __restrict__ off1, const float* __restrict__ off2,
                                const float* __restrict__ Wh, const float* __restrict__ bh,
                                const float* __restrict__ Wo, const float* __restrict__ bo,
                                float* __restrict__ A1, float* __restrict__ A2,
                                const float* __restrict__ W1, const float* __restrict__ W2,
                                const float* __restrict__ W3,
                                unsigned short* __restrict__ W1p, unsigned short* __restrict__ W2p,
                                unsigned short* __restrict__ W3p) {
    __shared__ float U[2304];     // transpose tile (1600 used) | A staging (2304)
    int blk = blockIdx.x;
    int tid = threadIdx.x;
    if (blk < TRB) {
        int n0 = blk * 64;
        for (int r = tid; r < 24 * 64; r += 256) {
            int cb = r >> 6;
            int nn = r & 63;
            U[nn * 25 + cb] = x[cb * N1C + n0 + nn];
        }
        __syncthreads();
        for (int w = tid; w < 64 * 24; w += 256) {
            int nn = w / 24;
            int u = w - nn * 24;
            X0[(n0 + nn) * 24 + u] = f2bf(U[nn * 25 + u]);
        }
    } else if (blk < TRB + MLB) {
        int bi = blk - TRB;
        int idx = bi * 256 + tid;
        const float* offp;
        if (idx < N2C * 9) offp = off1 + idx * 2;
        else offp = off2 + (idx - N2C * 9) * 2;
        float o0 = offp[0], o1 = offp[1];
        float out[9];
#pragma unroll
        for (int t = 0; t < 9; t++) out[t] = bo[t];
#pragma unroll
        for (int h = 0; h < 32; h++) {
            float hv = fmaxf(o0 * Wh[h] + o1 * Wh[32 + h] + bh[h], 0.f);
#pragma unroll
            for (int t = 0; t < 9; t++) out[t] += hv * Wo[h * 9 + t];
        }
#pragma unroll
        for (int t = 0; t < 9; t++) U[tid * 9 + t] = out[t];   // stride 9: conflict-free
        __syncthreads();
        float* dst = (bi < 441) ? (A1 + (size_t)bi * 2304)
                                : (A2 + (size_t)(bi - 441) * 2304);
        for (int i = tid; i < 2304; i += 256) dst[i] = U[i];   // coalesced
    } else {
        int i = (blk - TRB - MLB) * 256 + tid;
        if (i < 1024) pad_one(i, W1, W1p, 32, 3, 1);
        else if (i < 10240) pad_one(i - 1024, W2, W2p, 32, 32, 9);
        else pad_one(i - 10240, W3, W3p, 64, 32, 9);
    }
}

// ---------------- conv1: CIN=3 gather+weight -> LDS S -> MFMA (verified round-7 form) ----------------
template <int CIN, int MW, bool HAS_BN>   // instantiated with CIN=3 only
__global__ __launch_bounds__(256, 4)
void conv_kernel(const unsigned short* __restrict__ Xin,
                 const int* __restrict__ nbr,
                 const float* __restrict__ A,
                 const unsigned short* __restrict__ Wp,
                 const float* __restrict__ bias,
                 const float* __restrict__ bnsc,
                 const float* __restrict__ bnsh,
                 unsigned short* __restrict__ Yb,
                 double* __restrict__ Part) {
    constexpr int OC = MW * 16;
    constexpr int KREAL = 9 * CIN;
    constexpr int KROW = (KREAL + 31) & ~31;
    constexpr int KT = KROW / 32;
    constexpr int KSTR = KROW + 8;
    constexpr int PARTS = 256 / OC;
    constexpr int PCOLS = 64 / PARTS;
    constexpr int OSH = (OC == 32) ? 5 : 6;
    constexpr int YSTR = OC + 4;
    constexpr int SB1 = 64 * KSTR * 2;
    constexpr int SB2 = 64 * YSTR * 4 + PARTS * 2 * OC * 4;
    constexpr int SBYTES = SB1 > SB2 ? SB1 : SB2;
    __shared__ alignas(16) char Sraw[SBYTES];
    __shared__ float a_lds[8 * 81];
    short* S = (short*)Sraw;

    int tid = threadIdx.x;
    int tile = blockIdx.x;
    int n0 = tile * 8;

    for (int i = tid; i < 64 * KSTR; i += 256) S[i] = 0;   // zero pad slots
    for (int i = tid; i < 648; i += 256) a_lds[i] = A[(size_t)n0 * 81 + i];
    __syncthreads();
    if (tid < 192) {
        int nsub = tid / 24;
        int u = tid - nsub * 24;          // u = b*3+c
        int b = u / 3, c = u - b * 3;
        int n = n0 + nsub;
        const int* nb = nbr + n * 9;
        const float* Ar = a_lds + nsub * 81;
        float s[9];
#pragma unroll
        for (int t = 0; t < 9; t++) s[t] = 0.f;
#pragma unroll
        for (int k = 0; k < 9; k++) {
            float f = bf2f(Xin[nb[k] * 24 + u]);
#pragma unroll
            for (int t = 0; t < 9; t++) s[t] = fmaf(Ar[k * 9 + t], f, s[t]);
        }
        int col = nsub * 8 + b;
#pragma unroll
        for (int t = 0; t < 9; t++) S[col * KSTR + t * 3 + c] = (short)f2bf(s[t]);
    }
    __syncthreads();

    int lane = tid & 63, wv = tid >> 6, q = lane >> 4, cl = lane & 15;
    int colg = wv * 16 + cl;

    const bf16x8* wf = (const bf16x8*)Wp;
    f32x4 acc[MW];
#pragma unroll
    for (int m = 0; m < MW; m++) acc[m] = (f32x4){0.f, 0.f, 0.f, 0.f};
#pragma unroll
    for (int kt = 0; kt < KT; kt++) {
        bf16x8 bfr = *(const bf16x8*)&S[colg * KSTR + kt * 32 + q * 8];
#pragma unroll
        for (int m = 0; m < MW; m++) {
            const bf16x8* wg = wf + (m >> 1) * (KT * 128);
            bf16x8 am = wg[(kt * 4 + q) * 32 + cl + (m & 1) * 16];
            acc[m] = __builtin_amdgcn_mfma_f32_16x16x32_bf16(am, bfr, acc[m], 0, 0, 0);
        }
    }
    __syncthreads();

    float* Yf = (float*)Sraw;
    float* P2f = Yf + 64 * YSTR;
    int C = tile * 64 + colg;
#pragma unroll
    for (int m = 0; m < MW; m++) {
        f32x4 v;
#pragma unroll
        for (int i = 0; i < 4; i++) v[i] = acc[m][i] + bias[m * 16 + q * 4 + i];
        *(f32x4*)&Yf[colg * YSTR + m * 16 + q * 4] = v;
        uint2 pk;
        pk.x = cvtpk(v[0], v[1]);
        pk.y = cvtpk(v[2], v[3]);
        *(uint2*)&Yb[(size_t)C * OC + m * 16 + q * 4] = pk;
    }
    __syncthreads();
    {
        int o = tid & (OC - 1);
        int part = tid >> OSH;
        float s = 0.f, qq = 0.f;
#pragma unroll
        for (int i = 0; i < PCOLS; i++) {
            float y = Yf[(part * PCOLS + i) * YSTR + o];
            s += y;
            qq += y * y;
        }
        P2f[part * 2 * OC + o] = s;
        P2f[part * 2 * OC + OC + o] = qq;
    }
    __syncthreads();
    if (tid < 2 * OC) {
        double v = 0.0;
#pragma unroll
        for (int p = 0; p < PARTS; p++) v += (double)P2f[p * 2 * OC + tid];
        Part[(size_t)tid * NT_TILES + tile] = v;
    }
}

// ---------------- conv32: K-SPLIT two-pass MFMA, half-size S (21.5KB) -> 6 blocks/CU ----------------
// Pass 0: taps 0-4 -> S -> MFMA kt 0-4. Regather (L2-hot; frees fu regs across first MFMA,
// sched_barrier pins it). Pass 1: taps 5-8 reuse same S. S is wave-private (r10-verified:
// same-wave DS ordering needs no barrier). Epilogue = r7-verified Yf/P2f form aliased into S.
template <int MW>   // MW = OC/16
__global__ __launch_bounds__(256, 4)
void conv32_kernel(const unsigned short* __restrict__ Xin,
                   const int* __restrict__ nbr,
                   const float* __restrict__ A,
                   const unsigned short* __restrict__ Wp,
                   const float* __restrict__ bias,
                   const float* __restrict__ bnsc,
                   const float* __restrict__ bnsh,
                   unsigned short* __restrict__ Yb,
                   double* __restrict__ Part) {
    constexpr int OC = MW * 16;
    constexpr int PARTS = 256 / OC;           // 8 / 4
    constexpr int PCOLS = 64 / PARTS;         // 8 / 16
    constexpr int OSH = (OC == 32) ? 5 : 6;
    constexpr int YSTR = OC + 4;
    constexpr int KSTR2 = 168;                // half-K stride: 160 ch + 8 pad (uint2-safe)
    __shared__ alignas(16) short S[64 * KSTR2];   // 21504 B (epilogue Yf/P2f alias: <=19456 B)
    __shared__ float a_lds[648];

    int tid = threadIdx.x;
    int tile = blockIdx.x;
    int n0 = tile * 8;
    int wv = __builtin_amdgcn_readfirstlane(tid >> 6);
    int lane = tid & 63;
    int b = lane >> 3, c4 = lane & 7;
    int q = lane >> 4, cl = lane & 15;
    int colg = wv * 16 + cl;

    float4 scv = *(const float4*)&bnsc[4 * c4];
    float4 shv = *(const float4*)&bnsh[4 * c4];
    const uint2* Xd = (const uint2*)Xin;      // node row = 64 uint2 (512B)

    uint2 fu[18];
#pragma unroll
    for (int gg = 0; gg < 2; gg++)
#pragma unroll
        for (int k = 0; k < 9; k++) {
            int j = nbr[(n0 + wv * 2 + gg) * 9 + k];   // wave-uniform -> s_load
            fu[gg * 9 + k] = Xd[(size_t)j * 64 + lane];
        }
    for (int i = tid; i < 648; i += 256) a_lds[i] = A[(size_t)n0 * 81 + i];
    __syncthreads();                          // a_lds ready (gathers still in flight)

    const bf16x8* wf = (const bf16x8*)Wp;
    f32x4 acc[MW];
#pragma unroll
    for (int m = 0; m < MW; m++) acc[m] = (f32x4){0.f, 0.f, 0.f, 0.f};

    // ---- pass 0: taps 0..4 -> S (own 16 cols) -> MFMA kt 0..4 ----
#pragma unroll
    for (int gg = 0; gg < 2; gg++) {
        const float* Ar = a_lds + (wv * 2 + gg) * 81;
        float s0[5], s1[5], s2[5], s3[5];
#pragma unroll
        for (int t = 0; t < 5; t++) { s0[t] = 0.f; s1[t] = 0.f; s2[t] = 0.f; s3[t] = 0.f; }
#pragma unroll
        for (int k = 0; k < 9; k++) {
            uint2 u = fu[gg * 9 + k];
            float f0 = fmaxf(fmaf(bflo(u.x), scv.x, shv.x), 0.f);
            float f1 = fmaxf(fmaf(bfhi(u.x), scv.y, shv.y), 0.f);
            float f2 = fmaxf(fmaf(bflo(u.y), scv.z, shv.z), 0.f);
            float f3 = fmaxf(fmaf(bfhi(u.y), scv.w, shv.w), 0.f);
#pragma unroll
            for (int t = 0; t < 5; t++) {
                float a = Ar[k * 9 + t];
                s0[t] = fmaf(a, f0, s0[t]);
                s1[t] = fmaf(a, f1, s1[t]);
                s2[t] = fmaf(a, f2, s2[t]);
                s3[t] = fmaf(a, f3, s3[t]);
            }
        }
        int col = (wv * 2 + gg) * 8 + b;
        uint2* Srow = (uint2*)&S[col * KSTR2];
#pragma unroll
        for (int t = 0; t < 5; t++) {
            uint2 pk;
            pk.x = cvtpk(s0[t], s1[t]);
            pk.y = cvtpk(s2[t], s3[t]);
            Srow[t * 8 + c4] = pk;              // short off = t*32 + 4*c4
        }
    }
#pragma unroll
    for (int kt = 0; kt < 5; kt++) {
        bf16x8 bfr = *(const bf16x8*)&S[colg * KSTR2 + kt * 32 + q * 8];
#pragma unroll
        for (int m = 0; m < MW; m++) {
            const bf16x8* wg = wf + (m >> 1) * (9 * 128);
            bf16x8 am = wg[(kt * 4 + q) * 32 + cl + (m & 1) * 16];
            acc[m] = __builtin_amdgcn_mfma_f32_16x16x32_bf16(am, bfr, acc[m], 0, 0, 0);
        }
    }
    __builtin_amdgcn_sched_barrier(0);        // pin regather AFTER pass-0 MFMA (fu regs freed)

    // ---- regather (L2-hot) + pass 1: taps 5..8 reuse S -> MFMA kt 5..8 ----
#pragma unroll
    for (int gg = 0; gg < 2; gg++)
#pragma unroll
        for (int k = 0; k < 9; k++) {
            int j = nbr[(n0 + wv * 2 + gg) * 9 + k];
            fu[gg * 9 + k] = Xd[(size_t)j * 64 + lane];
        }
#pragma unroll
    for (int gg = 0; gg < 2; gg++) {
        const float* Ar = a_lds + (wv * 2 + gg) * 81;
        float s0[4], s1[4], s2[4], s3[4];
#pragma unroll
        for (int t = 0; t < 4; t++) { s0[t] = 0.f; s1[t] = 0.f; s2[t] = 0.f; s3[t] = 0.f; }
#pragma unroll
        for (int k = 0; k < 9; k++) {
            uint2 u = fu[gg * 9 + k];
            float f0 = fmaxf(fmaf(bflo(u.x), scv.x, shv.x), 0.f);
            float f1 = fmaxf(fmaf(bfhi(u.x), scv.y, shv.y), 0.f);
            float f2 = fmaxf(fmaf(bflo(u.y), scv.z, shv.z), 0.f);
            float f3 = fmaxf(fmaf(bfhi(u.y), scv.w, shv.w), 0.f);
#pragma unroll
            for (int t = 0; t < 4; t++) {
                float a = Ar[k * 9 + 5 + t];
                s0[t] = fmaf(a, f0, s0[t]);
                s1[t] = fmaf(a, f1, s1[t]);
                s2[t] = fmaf(a, f2, s2[t]);
                s3[t] = fmaf(a, f3, s3[t]);
            }
        }
        int col = (wv * 2 + gg) * 8 + b;
        uint2* Srow = (uint2*)&S[col * KSTR2];
#pragma unroll
        for (int t = 0; t < 4; t++) {
            uint2 pk;
            pk.x = cvtpk(s0[t], s1[t]);
            pk.y = cvtpk(s2[t], s3[t]);
            Srow[t * 8 + c4] = pk;              // same-wave WAR on S: DS in-order, safe
        }
    }
#pragma unroll
    for (int kt = 0; kt < 4; kt++) {
        bf16x8 bfr = *(const bf16x8*)&S[colg * KSTR2 + kt * 32 + q * 8];
#pragma unroll
        for (int m = 0; m < MW; m++) {
            const bf16x8* wg = wf + (m >> 1) * (9 * 128);
            bf16x8 am = wg[((5 + kt) * 4 + q) * 32 + cl + (m & 1) * 16];
            acc[m] = __builtin_amdgcn_mfma_f32_16x16x32_bf16(am, bfr, acc[m], 0, 0, 0);
        }
    }

    // ---- epilogue (r7-verified): Yf/P2f alias S; barrier first (Yf rows cross wave slices) ----
    __syncthreads();
    float* Yf = (float*)S;                // [64][YSTR]
    float* P2f = Yf + 64 * YSTR;          // [PARTS][2*OC]; total <= 19456 B < 21504 B
    int C = tile * 64 + colg;
#pragma unroll
    for (int m = 0; m < MW; m++) {
        f32x4 v;
#pragma unroll
        for (int i = 0; i < 4; i++) v[i] = acc[m][i] + bias[m * 16 + q * 4 + i];
        *(f32x4*)&Yf[colg * YSTR + m * 16 + q * 4] = v;
        uint2 pk;
        pk.x = cvtpk(v[0], v[1]);
        pk.y = cvtpk(v[2], v[3]);
        *(uint2*)&Yb[(size_t)C * OC + m * 16 + q * 4] = pk;
    }
    __syncthreads();
    {
        int o = tid & (OC - 1);
        int part = tid >> OSH;
        float s = 0.f, qq = 0.f;
#pragma unroll
        for (int i = 0; i < PCOLS; i++) {
            float y = Yf[(part * PCOLS + i) * YSTR + o];
            s += y;
            qq += y * y;
        }
        P2f[part * 2 * OC + o] = s;
        P2f[part * 2 * OC + OC + o] = qq;
    }
    __syncthreads();
    if (tid < 2 * OC) {
        double v = 0.0;
#pragma unroll
        for (int p = 0; p < PARTS; p++) v += (double)P2f[p * 2 * OC + tid];
        Part[(size_t)tid * NT_TILES + tile] = v;   // transposed: coalesced in bn_reduce
    }
}

// ---------------- BN reduce+finalize: one block per channel ----------------
__global__ __launch_bounds__(256, 8)
void bn_reduce(const double* __restrict__ Part,
               const float* __restrict__ g, const float* __restrict__ be,
               float* __restrict__ sc, float* __restrict__ sh, int OC) {
    int o = blockIdx.x;
    int tid = threadIdx.x;
    const double* ps = Part + (size_t)o * NT_TILES;
    const double* pq = Part + (size_t)(OC + o) * NT_TILES;
    double s = 0.0, q = 0.0;
    for (int t = tid; t < NT_TILES; t += 256) {
        s += ps[t];
        q += pq[t];
    }
#pragma unroll
    for (int d = 1; d < 64; d <<= 1) {
        s += __shfl_xor(s, d);
        q += __shfl_xor(q, d);
    }
    __shared__ double red[8];
    int wv = tid >> 6;
    if ((tid & 63) == 0) { red[wv] = s; red[4 + wv] = q; }
    __syncthreads();
    if (tid == 0) {
        double S = red[0] + red[1] + red[2] + red[3];
        double Q = red[4] + red[5] + red[6] + red[7];
        double cnt = (double)N2C * 8.0;
        double mean = S / cnt;
        double var = Q / cnt - mean * mean;
        double rs = 1.0 / sqrt(var + 1e-5);
        double scale = (double)g[o] * rs;
        sc[o] = (float)scale;
        sh[o] = (float)((double)be[o] - mean * scale);
    }
}

// ---------------- pool: 2 m per 256-thr block; thread owns a channel pair ----------------
__global__ __launch_bounds__(256, 8)
void pool_kernel(const unsigned short* __restrict__ Y3, const int* __restrict__ pidx,
                 const float* __restrict__ sc, const float* __restrict__ sh,
                 float* __restrict__ out) {
    int m0 = blockIdx.x * 2;
    int tid = threadIdx.x;      // b*32 + o2  (o2 = channel pair)
    int o2 = tid & 31;
    int b = tid >> 5;
    float s0 = sc[2 * o2], h0 = sh[2 * o2];
    float s1 = sc[2 * o2 + 1], h1 = sh[2 * o2 + 1];
    const unsigned* Y3u = (const unsigned*)Y3;
    int j0[9], j1[9];
#pragma unroll
    for (int k = 0; k < 9; k++) {
        j0[k] = pidx[m0 * 9 + k];
        j1[k] = pidx[m0 * 9 + 9 + k];
    }
    unsigned u0[9], u1[9];                      // all 18 gathers in flight
#pragma unroll
    for (int k = 0; k < 9; k++) u0[k] = Y3u[(size_t)j0[k] * 256 + tid];
#pragma unroll
    for (int k = 0; k < 9; k++) u1[k] = Y3u[(size_t)j1[k] * 256 + tid];
    float a0 = 0.f, a1 = 0.f, c0 = 0.f, c1 = 0.f;
#pragma unroll
    for (int k = 0; k < 9; k++) {
        a0 = fmaxf(a0, fmaf(bflo(u0[k]), s0, h0));
        a1 = fmaxf(a1, fmaf(bfhi(u0[k]), s1, h1));
        c0 = fmaxf(c0, fmaf(bflo(u1[k]), s0, h0));
        c1 = fmaxf(c1, fmaf(bfhi(u1[k]), s1, h1));
    }
    float2 r0 = {a0, c0};       // channel 2*o2,   m0 / m0+1
    float2 r1 = {a1, c1};       // channel 2*o2+1, m0 / m0+1
    *(float2*)(out + (size_t)(b * 64 + 2 * o2) * 3136 + m0) = r0;
    *(float2*)(out + (size_t)(b * 64 + 2 * o2 + 1) * 3136 + m0) = r1;
}

extern "C" void kernel_launch(void* const* d_in, const int* in_sizes, int n_in,
                              void* d_out, int out_size, void* d_ws, size_t ws_size,
                              hipStream_t stream) {
    const float* x    = (const float*)d_in[0];
    const int*   nbr1 = (const int*)d_in[1];
    const float* off1 = (const float*)d_in[2];
    const int*   nbr2 = (const int*)d_in[3];
    const float* off2 = (const float*)d_in[4];
    const int*   pidx = (const int*)d_in[5];
    const float* Wh   = (const float*)d_in[6];
    const float* bh   = (const float*)d_in[7];
    const float* Wo   = (const float*)d_in[8];
    const float* bo   = (const float*)d_in[9];
    const float* W1   = (const float*)d_in[10];
    const float* b1   = (const float*)d_in[11];
    const float* W2   = (const float*)d_in[12];
    const float* b2   = (const float*)d_in[13];
    const float* W3   = (const float*)d_in[14];
    const float* b3   = (const float*)d_in[15];
    const float* g1   = (const float*)d_in[16];
    const float* be1  = (const float*)d_in[17];
    const float* g2   = (const float*)d_in[18];
    const float* be2  = (const float*)d_in[19];
    const float* g3   = (const float*)d_in[20];
    const float* be3  = (const float*)d_in[21];

    char* ws = (char*)d_ws;
    size_t off = 0;
    auto alloc = [&](size_t bytes) -> void* {
        void* p = ws + off;
        off += (bytes + 255) & ~(size_t)255;
        return p;
    };
    unsigned short* X0b = (unsigned short*)alloc((size_t)N1C * 24 * 2);   // 2.4MB
    float* A1 = (float*)alloc((size_t)N2C * 81 * 4);                      // 4.1MB
    float* A2 = (float*)alloc((size_t)N2C * 81 * 4);                      // 4.1MB
    unsigned short* Y1b = (unsigned short*)alloc((size_t)N2C * 8 * 32 * 2);  // 6.4MB
    unsigned short* Y2b = (unsigned short*)alloc((size_t)N2C * 8 * 32 * 2);  // 6.4MB
    unsigned short* Y3b = (unsigned short*)alloc((size_t)N2C * 8 * 64 * 2);  // 12.8MB
    unsigned short* W1p = (unsigned short*)alloc(32 * 32 * 2);
    unsigned short* W2p = (unsigned short*)alloc(32 * 288 * 2);
    unsigned short* W3p = (unsigned short*)alloc(64 * 288 * 2);
    double* Part  = (double*)alloc((size_t)NT_TILES * 128 * 8);           // 1.6MB
    float*  scbuf = (float*)alloc(256 * 4);

    float* sc1 = scbuf;       float* sh1 = scbuf + 32;
    float* sc2 = scbuf + 64;  float* sh2 = scbuf + 96;
    float* sc3 = scbuf + 128; float* sh3 = scbuf + 192;

    prologue_kernel<<<TRB + MLB + PWB, 256, 0, stream>>>(
        x, X0b, off1, off2, Wh, bh, Wo, bo, A1, A2, W1, W2, W3, W1p, W2p, W3p);

    conv_kernel<3, 2, false><<<NT_TILES, 256, 0, stream>>>(
        X0b, nbr1, A1, W1p, b1, nullptr, nullptr, Y1b, Part);
    bn_reduce<<<32, 256, 0, stream>>>(Part, g1, be1, sc1, sh1, 32);

    conv32_kernel<2><<<NT_TILES, 256, 0, stream>>>(
        Y1b, nbr2, A2, W2p, b2, sc1, sh1, Y2b, Part);
    bn_reduce<<<32, 256, 0, stream>>>(Part, g2, be2, sc2, sh2, 32);

    conv32_kernel<4><<<NT_TILES, 256, 0, stream>>>(
        Y2b, nbr2, A2, W3p, b3, sc2, sh2, Y3b, Part);
    bn_reduce<<<64, 256, 0, stream>>>(Part, g3, be3, sc3, sh3, 64);

    pool_kernel<<<N3C / 2, 256, 0, stream>>>(Y3b, pidx, sc3, sh3, (float*)d_out);
}